// Round 1
// baseline (51.106 us; speedup 1.0000x reference)
//
#include <hip/hip_runtime.h>
#include <math.h>

// Problem constants (reference: X shape (N=32, D=128, L=8192), f32)
#define N_BATCH 32
#define D_DIM   128
#define HALF    64
#define SEQ_L   8192
#define L_VEC4  (SEQ_L / 4)          // 2048 float4 per row
#define TAB_ELEMS (HALF * SEQ_L)     // 524288 angles
#define TAB_BYTES (TAB_ELEMS * 2 * sizeof(float))  // c + s tables = 4 MiB

// ---------------------------------------------------------------------------
// Kernel 1: build cos/sin tables for angle(i,k) = theta_i * k, theta_i =
// 10000^(i/64). theta computed in DOUBLE then rounded to f32 -> correctly
// rounded f32 theta (must bit-match the host reference's powf; a 1-ulp theta
// error -> ~8 rad angle error at k=8191). angle = f32 multiply (IEEE, matches
// numpy). sincosf = OCML full Payne-Hanek reduction (args reach ~7e7 rad).
// ---------------------------------------------------------------------------
__global__ void rope_tables(float* __restrict__ ctab, float* __restrict__ stab) {
    int idx = blockIdx.x * blockDim.x + threadIdx.x;
    if (idx >= TAB_ELEMS) return;
    int i = idx >> 13;        // / 8192
    int k = idx & (SEQ_L - 1);
    float theta = (float)pow(10000.0, (double)i * (1.0 / 64.0));
    float angle = theta * (float)k;    // exact same f32 product as reference
    float s, c;
    sincosf(angle, &s, &c);            // no fast-math: full range reduction
    ctab[idx] = c;
    stab[idx] = s;
}

// ---------------------------------------------------------------------------
// Kernel 2: apply rotation, float4-vectorized along k (coalesced).
// out[n,i,k]      = c*x1 - s*x2
// out[n,i+64,k]   = s*x1 + c*x2
// ---------------------------------------------------------------------------
__global__ void rope_apply(const float4* __restrict__ X,
                           float4* __restrict__ out,
                           const float4* __restrict__ ctab,
                           const float4* __restrict__ stab) {
    int tid = blockIdx.x * blockDim.x + threadIdx.x;   // 0 .. 32*64*2048-1
    if (tid >= N_BATCH * HALF * L_VEC4) return;
    int k4 = tid & (L_VEC4 - 1);
    int i  = (tid >> 11) & (HALF - 1);
    int n  = tid >> 17;

    int tidx = (i << 11) + k4;
    float4 c = ctab[tidx];
    float4 s = stab[tidx];
    int base1 = ((n * D_DIM + i) << 11) + k4;
    int base2 = ((n * D_DIM + i + HALF) << 11) + k4;
    float4 x1 = X[base1];
    float4 x2 = X[base2];

    float4 o1, o2;
    o1.x = c.x * x1.x - s.x * x2.x;  o2.x = s.x * x1.x + c.x * x2.x;
    o1.y = c.y * x1.y - s.y * x2.y;  o2.y = s.y * x1.y + c.y * x2.y;
    o1.z = c.z * x1.z - s.z * x2.z;  o2.z = s.z * x1.z + c.z * x2.z;
    o1.w = c.w * x1.w - s.w * x2.w;  o2.w = s.w * x1.w + c.w * x2.w;

    out[base1] = o1;
    out[base2] = o2;
}

// Fallback if d_ws is too small for the tables: compute sincos inline
// (slower but correct).
__global__ void rope_apply_inline(const float4* __restrict__ X,
                                  float4* __restrict__ out) {
    int tid = blockIdx.x * blockDim.x + threadIdx.x;
    if (tid >= N_BATCH * HALF * L_VEC4) return;
    int k4 = tid & (L_VEC4 - 1);
    int i  = (tid >> 11) & (HALF - 1);
    int n  = tid >> 17;

    float theta = (float)pow(10000.0, (double)i * (1.0 / 64.0));
    float4 c, s;
    {
        float k0 = (float)(k4 * 4);
        sincosf(theta * k0,          &s.x, &c.x);
        sincosf(theta * (k0 + 1.0f), &s.y, &c.y);
        sincosf(theta * (k0 + 2.0f), &s.z, &c.z);
        sincosf(theta * (k0 + 3.0f), &s.w, &c.w);
    }
    int base1 = ((n * D_DIM + i) << 11) + k4;
    int base2 = ((n * D_DIM + i + HALF) << 11) + k4;
    float4 x1 = X[base1];
    float4 x2 = X[base2];
    float4 o1, o2;
    o1.x = c.x * x1.x - s.x * x2.x;  o2.x = s.x * x1.x + c.x * x2.x;
    o1.y = c.y * x1.y - s.y * x2.y;  o2.y = s.y * x1.y + c.y * x2.y;
    o1.z = c.z * x1.z - s.z * x2.z;  o2.z = s.z * x1.z + c.z * x2.z;
    o1.w = c.w * x1.w - s.w * x2.w;  o2.w = s.w * x1.w + c.w * x2.w;
    out[base1] = o1;
    out[base2] = o2;
}

extern "C" void kernel_launch(void* const* d_in, const int* in_sizes, int n_in,
                              void* d_out, int out_size, void* d_ws, size_t ws_size,
                              hipStream_t stream) {
    const float4* X  = (const float4*)d_in[0];
    float4* out      = (float4*)d_out;

    const int apply_threads = N_BATCH * HALF * L_VEC4;   // 4,194,304
    const int block = 256;

    if (ws_size >= TAB_BYTES) {
        float* ctab = (float*)d_ws;
        float* stab = ctab + TAB_ELEMS;
        rope_tables<<<(TAB_ELEMS + block - 1) / block, block, 0, stream>>>(ctab, stab);
        rope_apply<<<(apply_threads + block - 1) / block, block, 0, stream>>>(
            X, out, (const float4*)ctab, (const float4*)stab);
    } else {
        rope_apply_inline<<<(apply_threads + block - 1) / block, block, 0, stream>>>(X, out);
    }
}

// Round 2
// 44.389 us; speedup vs baseline: 1.1513x; 1.1513x over previous
//
#include <hip/hip_runtime.h>
#include <math.h>

// RoPE, X shape (N=32, D=128, L=8192) f32.
// Fused single kernel: each thread owns one (i, k4) pair -> computes 4
// sincos values ONCE, then applies the rotation for NN=8 batches. Total
// sincos lane-calls = 64*2048*4groups*4 = 2M (~2 us VALU, hidden under
// memory). Traffic = pure 2*128 MiB minimum, no table round-trip, one
// dispatch.
//
// Numerics (validated in R1): theta computed in double then rounded to f32
// (correctly-rounded f32 theta, matches np's powf to the bit); angle is the
// IEEE f32 product theta*k (k exact in f32 up to 8191); sincosf = OCML with
// full Payne-Hanek reduction (angles reach ~7e7 rad). absmax was 1.6e-2 vs
// 0.109 threshold.

#define N_BATCH 32
#define D_DIM   128
#define HALF    64
#define SEQ_L   8192
#define L_VEC4  (SEQ_L / 4)      // 2048 float4 per row
#define NN      8                // batches per thread
#define NGRP    (N_BATCH / NN)   // 4
#define TOTAL_THREADS (NGRP * HALF * L_VEC4)   // 524288

__global__ __launch_bounds__(256) void rope_fused(const float4* __restrict__ X,
                                                  float4* __restrict__ out) {
    int tid = blockIdx.x * blockDim.x + threadIdx.x;
    if (tid >= TOTAL_THREADS) return;
    int k4 = tid & (L_VEC4 - 1);
    int i  = (tid >> 11) & (HALF - 1);
    int g  = tid >> 17;              // 0..NGRP-1

    // theta_i = 10000^(i/64), correctly rounded to f32 via double pow.
    float theta = (float)pow(10000.0, (double)i * (1.0 / 64.0));

    float k0 = (float)(k4 * 4);
    float4 c, s;
    sincosf(theta * k0,          &s.x, &c.x);
    sincosf(theta * (k0 + 1.0f), &s.y, &c.y);
    sincosf(theta * (k0 + 2.0f), &s.z, &c.z);
    sincosf(theta * (k0 + 3.0f), &s.w, &c.w);

    int n0 = g * NN;
    #pragma unroll
    for (int t = 0; t < NN; ++t) {
        int n = n0 + t;
        int b1 = ((n * D_DIM + i) << 11) + k4;          // (n, i, k)
        int b2 = b1 + (HALF << 11);                     // (n, i+64, k)
        float4 x1 = X[b1];
        float4 x2 = X[b2];
        float4 o1, o2;
        o1.x = c.x * x1.x - s.x * x2.x;  o2.x = s.x * x1.x + c.x * x2.x;
        o1.y = c.y * x1.y - s.y * x2.y;  o2.y = s.y * x1.y + c.y * x2.y;
        o1.z = c.z * x1.z - s.z * x2.z;  o2.z = s.z * x1.z + c.z * x2.z;
        o1.w = c.w * x1.w - s.w * x2.w;  o2.w = s.w * x1.w + c.w * x2.w;
        out[b1] = o1;
        out[b2] = o2;
    }
}

extern "C" void kernel_launch(void* const* d_in, const int* in_sizes, int n_in,
                              void* d_out, int out_size, void* d_ws, size_t ws_size,
                              hipStream_t stream) {
    const float4* X = (const float4*)d_in[0];
    float4* out     = (float4*)d_out;
    const int block = 256;
    rope_fused<<<TOTAL_THREADS / block, block, 0, stream>>>(X, out);
}